// Round 6
// baseline (241.540 us; speedup 1.0000x reference)
//
#include <hip/hip_runtime.h>
#include <hip/hip_bf16.h>

#define HEADS 4
#define DIMH  32
#define HID   128
#define DIM   128
#define NSP   4096
// 10 * log2(e) folded into Qt at k_ntr time; attention uses exp2 directly.
#define QSCALE_LOG2E 14.426950408889634f

typedef __attribute__((ext_vector_type(4)))  float f32x4;
typedef __attribute__((ext_vector_type(16))) float f32x16;
typedef __attribute__((ext_vector_type(8)))  short s16x8;

// ---------------- fused QKV GEMM (fp32 VALU, blockIdx-uniform weights) ----------------
// grid = 24 chunks (16 out-rows each) x 32 col-tiles (256 cols), block 256.
// chunk 0..7 -> Q rows from x; 8..15 -> K rows from y; 16..23 -> V rows from y (bf16).
__global__ __launch_bounds__(256, 4) void k_qkv(const float* __restrict__ x,
                                                const float* __restrict__ y,
                                                const float* __restrict__ w,
                                                float* __restrict__ Qf,
                                                float* __restrict__ Kf,
                                                __hip_bfloat16* __restrict__ Vb) {
  int ct = blockIdx.x & 31, ch = blockIdx.x >> 5;   // ch 0..23
  int g = ct * 256 + threadIdx.x;
  int b = g >> 12, n = g & 4095;
  const float* src = (ch < 8 ? x : y) + (size_t)b * DIM * NSP + n;
  int wrow = (ch < 8 ? ch * 16 : HID + (ch - 8) * 16);
  float acc[16];
#pragma unroll
  for (int i = 0; i < 16; ++i) acc[i] = 0.f;
#pragma unroll 1
  for (int c0 = 0; c0 < DIM; c0 += 32) {
    float cache[32];
#pragma unroll
    for (int cc = 0; cc < 32; ++cc) cache[cc] = src[(size_t)(c0 + cc) * NSP];
#pragma unroll
    for (int cc = 0; cc < 32; ++cc)
#pragma unroll
      for (int i = 0; i < 16; ++i)
        acc[i] += w[(wrow + i) * DIM + c0 + cc] * cache[cc];
  }
  if (ch < 8) {
    float* dst = Qf + (size_t)b * HID * NSP + n;
#pragma unroll
    for (int i = 0; i < 16; ++i) dst[(size_t)(ch * 16 + i) * NSP] = acc[i];
  } else if (ch < 16) {
    float* dst = Kf + (size_t)b * HID * NSP + n;
#pragma unroll
    for (int i = 0; i < 16; ++i) dst[(size_t)((ch - 8) * 16 + i) * NSP] = acc[i];
  } else {
    __hip_bfloat16* dst = Vb + (size_t)b * HID * NSP + n;
#pragma unroll
    for (int i = 0; i < 16; ++i) dst[(size_t)((ch - 16) * 16 + i) * NSP] = __float2bfloat16(acc[i]);
  }
}

// ---------------- row norms (over spatial axis) for Q and K ----------------
__global__ __launch_bounds__(256) void k_norms(const float* __restrict__ Qf,
                                               const float* __restrict__ Kf,
                                               float* __restrict__ rn) {
  int row = blockIdx.x;  // 0..255 Q rows, 256..511 K rows
  const float* src = (row < 256 ? Qf + (size_t)row * NSP : Kf + (size_t)(row - 256) * NSP);
  float ss = 0.f;
  for (int i = threadIdx.x; i < NSP; i += 256) { float v = src[i]; ss += v * v; }
  for (int m = 32; m; m >>= 1) ss += __shfl_xor(ss, m);
  __shared__ float red[4];
  if ((threadIdx.x & 63) == 0) red[threadIdx.x >> 6] = ss;
  __syncthreads();
  if (threadIdx.x == 0) {
    float t = red[0] + red[1] + red[2] + red[3];
    rn[row] = 1.f / fmaxf(sqrtf(t), 1e-12f);
  }
}

// ---------------- normalize + transpose to [b,h,n,32] bf16 (Q gets exp2 scale) ----------------
__global__ __launch_bounds__(256) void k_ntr(const float* __restrict__ Qf,
                                             const float* __restrict__ Kf,
                                             const float* __restrict__ rn,
                                             __hip_bfloat16* __restrict__ Qt,
                                             __hip_bfloat16* __restrict__ Kt) {
  int id   = blockIdx.x;        // 2 tensors * 2 b * 4 h * 32 itiles
  int tens = id >> 8;
  int rem  = id & 255;
  int b = rem >> 7, h = (rem >> 5) & 3, it = rem & 31;
  const float* src = (tens ? Kf : Qf) + ((size_t)(b * HID + h * DIMH)) * NSP + it * 128;
  const float* rns = rn + tens * 256 + b * HID + h * DIMH;
  __hip_bfloat16* dst = (tens ? Kt : Qt) + ((size_t)(b * HEADS + h) * NSP + it * 128) * DIMH;

  __shared__ float tile[DIMH][132];
  int d  = threadIdx.x >> 3;
  int cb = (threadIdx.x & 7) * 16;
  float s = rns[d] * (tens ? 1.f : QSCALE_LOG2E);
#pragma unroll
  for (int k = 0; k < 16; ++k) tile[d][cb + k] = src[(size_t)d * NSP + cb + k] * s;
  __syncthreads();
  int i = threadIdx.x >> 1, dh = (threadIdx.x & 1) * 16;
  unsigned outw[8];
#pragma unroll
  for (int k = 0; k < 8; ++k) {
    __hip_bfloat16 a = __float2bfloat16(tile[dh + 2 * k][i]);
    __hip_bfloat16 c = __float2bfloat16(tile[dh + 2 * k + 1][i]);
    unsigned lo = *(unsigned short*)&a, hi = *(unsigned short*)&c;
    outw[k] = lo | (hi << 16);
  }
  *(uint4*)(dst + i * DIMH + dh)     = *(uint4*)outw;
  *(uint4*)(dst + i * DIMH + dh + 8) = *(uint4*)(outw + 4);
}

// ---------------- flash attention: 32x32x16 MFMA, in-register softmax ----------------
__device__ __forceinline__ unsigned cvtpk_bf16(float a, float b) {
  unsigned d;
  asm("v_cvt_pk_bf16_f32 %0, %1, %2" : "=v"(d) : "v"(a), "v"(b));
  return d;
}

struct K4 { s16x8 k[4]; };
struct V4 { s16x8 v[4]; };

__device__ __forceinline__ K4 ldK(const __hip_bfloat16* kp, int j0) {
  K4 f;
#pragma unroll
  for (int s2 = 0; s2 < 2; ++s2)
#pragma unroll
    for (int kh = 0; kh < 2; ++kh)
      f.k[s2 * 2 + kh] = *(const s16x8*)(kp + (size_t)(j0 + s2 * 32) * DIMH + kh * 16);
  return f;
}
__device__ __forceinline__ V4 ldV(const __hip_bfloat16* vp, int j0) {
  V4 f;
#pragma unroll
  for (int cc = 0; cc < 4; ++cc)
    f.v[cc] = *(const s16x8*)(vp + j0 + cc * 16);
  return f;
}

// One 32(q-rows) x 32(j) subtile: QK^T (2 MFMA), exp2, pack, PV (2 MFMA).
__device__ __forceinline__ void attn_sub(s16x8 k0, s16x8 k1, s16x8 v0, s16x8 v1,
                                         const s16x8* qb, f32x16& O, float& lsum) {
  f32x16 z = {};
  f32x16 s = __builtin_amdgcn_mfma_f32_32x32x16_bf16(k0, qb[0], z, 0, 0, 0);
  s        = __builtin_amdgcn_mfma_f32_32x32x16_bf16(k1, qb[1], s, 0, 0, 0);
  float p[16];
#pragma unroll
  for (int r = 0; r < 16; ++r) p[r] = __builtin_amdgcn_exp2f(s[r]);
  float t0 = 0.f, t1 = 0.f;
#pragma unroll
  for (int r = 0; r < 16; r += 2) { t0 += p[r]; t1 += p[r + 1]; }
  lsum += t0 + t1;
  unsigned wA[4], wB[4];
#pragma unroll
  for (int m = 0; m < 4; ++m) {
    wA[m] = cvtpk_bf16(p[4 * m], p[4 * m + 1]);
    wB[m] = cvtpk_bf16(p[4 * m + 2], p[4 * m + 3]);
  }
#define PV_CHUNK(c, vfrag)                                                     \
  {                                                                            \
    unsigned a0 = wA[2 * (c)], a1 = wA[2 * (c) + 1];                           \
    unsigned b0 = wB[2 * (c)], b1 = wB[2 * (c) + 1];                           \
    asm("v_permlane32_swap_b32 %0, %1" : "+v"(a0), "+v"(a1));                  \
    asm("v_permlane32_swap_b32 %0, %1" : "+v"(b0), "+v"(b1));                  \
    union { unsigned u[4]; s16x8 v; } pa;                                      \
    pa.u[0] = a0; pa.u[1] = b0; pa.u[2] = a1; pa.u[3] = b1;                    \
    O = __builtin_amdgcn_mfma_f32_32x32x16_bf16(pa.v, vfrag, O, 0, 0, 0);      \
  }
  PV_CHUNK(0, v0);
  PV_CHUNK(1, v1);
#undef PV_CHUNK
}

// block = 8 waves (one 32-row q-tile, 8-way j split), grid = 8 bh * 128 rtiles.
// 1024 blocks x 8 waves = 8192 waves -> 100% occupancy at VGPR<=64 (launch_bounds 512,8).
// Output written channel-major: Ot2[(bh*32+d)*NSP + n] via LDS transpose.
__global__ __launch_bounds__(512, 8) void k_attn(const __hip_bfloat16* __restrict__ Qt,
                                                 const __hip_bfloat16* __restrict__ Kt,
                                                 const __hip_bfloat16* __restrict__ Vb,
                                                 float* __restrict__ Ot2) {
  int bid = blockIdx.x;
  int swz = (bid & 7) * 128 + (bid >> 3);   // 1024 blocks, XCD-contiguous
  int bh = swz >> 7, rt = swz & 127;
  int tid = threadIdx.x, lane = tid & 63, wave = tid >> 6;  // wave = j-eighth
  int l31 = lane & 31, hi = lane >> 5;
  int i0 = rt * 32;

  const __hip_bfloat16* kp = Kt + ((size_t)bh * NSP + l31) * DIMH + hi * 8;
  const __hip_bfloat16* vp = Vb + ((size_t)bh * DIMH + l31) * NSP + hi * 8;
  const __hip_bfloat16* qp = Qt + ((size_t)bh * NSP + i0 + l31) * DIMH + hi * 8;
  s16x8 qb[2] = { *(const s16x8*)qp, *(const s16x8*)(qp + 16) };

  f32x16 O = {};
  float ls0 = 0.f, ls1 = 0.f;
  int jbase = wave * 512;

  for (int t = 0; t < 8; ++t) {
    int j0 = jbase + t * 64;
    K4 k = ldK(kp, j0);
    V4 v = ldV(vp, j0);
    attn_sub(k.k[0], k.k[1], v.v[0], v.v[1], qb, O, ls0);
    attn_sub(k.k[2], k.k[3], v.v[2], v.v[3], qb, O, ls1);
  }
  float lsum = ls0 + ls1;

  // ---- merge 8 j-eighths, divide by row sums, transpose to channel-major ----
  __shared__ float Olds[7][16][68];
  __shared__ float Llds[8][64];
  float lw = lsum + __shfl_xor(lsum, 32);   // per-row sum (row = l31)
  if (wave) {
#pragma unroll
    for (int r = 0; r < 16; ++r) Olds[wave - 1][r][lane] = O[r];
    Llds[wave][lane] = lw;
  }
  __syncthreads();
  if (wave == 0) {
    float ltot = lw;
#pragma unroll
    for (int w2 = 1; w2 < 8; ++w2) ltot += Llds[w2][lane];
    if (hi == 0) Llds[0][l31] = ltot;       // reindex by row (same-wave DS order)
#pragma unroll
    for (int r = 0; r < 16; ++r) {
      int i = (r & 3) + 8 * (r >> 2) + 4 * hi;
      float li = Llds[0][i];
      float sum = O[r];
#pragma unroll
      for (int w2 = 0; w2 < 7; ++w2) sum += Olds[w2][r][lane];
      Olds[0][r][lane] = sum / li;
    }
  }
  __syncthreads();
  // store: 32 d x 32 n; lanes cover n (coalesced 128B per d-row); 512 thr -> 2 d each
  {
    int n = tid & 31, dgrp = tid >> 5;       // dgrp 0..15, 2 d each
    int r = (n & 3) | ((n >> 3) << 2);
    int h2 = (n >> 2) & 1;
    float* obase = Ot2 + ((size_t)bh * DIMH) * NSP + i0 + n;
#pragma unroll
    for (int k2 = 0; k2 < 2; ++k2) {
      int d = dgrp * 2 + k2;
      obase[(size_t)d * NSP] = Olds[0][r][h2 * 32 + d];
    }
  }
}

// ---------------- output projection: channel GEMM over Ot2 ----------------
// grid = 8 chunks (16 outs) x 32 ct, block 256.
__global__ __launch_bounds__(256, 4) void k_proj(const float* __restrict__ Ot2,
                                                 const float* __restrict__ w,
                                                 const float* __restrict__ bias,
                                                 float* __restrict__ out) {
  int ct = blockIdx.x & 31, oc = blockIdx.x >> 5;   // oc 0..7
  int g = ct * 256 + threadIdx.x;
  int b = g >> 12, n = g & 4095;
  const float* op = Ot2 + (size_t)b * HID * NSP + n;
  float acc[16];
#pragma unroll
  for (int i = 0; i < 16; ++i) acc[i] = bias[oc * 16 + i];
#pragma unroll 1
  for (int c0 = 0; c0 < HID; c0 += 32) {
    float cache[32];
#pragma unroll
    for (int cc = 0; cc < 32; ++cc) cache[cc] = op[(size_t)(c0 + cc) * NSP];
#pragma unroll
    for (int cc = 0; cc < 32; ++cc)
#pragma unroll
      for (int i = 0; i < 16; ++i)
        acc[i] += w[(oc * 16 + i) * HID + c0 + cc] * cache[cc];
  }
  float* outb = out + (size_t)b * DIM * NSP + n;
#pragma unroll
  for (int i = 0; i < 16; ++i) outb[(size_t)(oc * 16 + i) * NSP] = acc[i];
}

extern "C" void kernel_launch(void* const* d_in, const int* in_sizes, int n_in,
                              void* d_out, int out_size, void* d_ws, size_t ws_size,
                              hipStream_t stream) {
  const float* x     = (const float*)d_in[0];
  const float* y     = (const float*)d_in[1];
  const float* w_qkv = (const float*)d_in[2];
  const float* w_out = (const float*)d_in[3];
  const float* b_out = (const float*)d_in[4];
  float* out = (float*)d_out;

  char* ws = (char*)d_ws;
  float* Qf           = (float*)(ws);                       // 4 MB
  float* Kf           = (float*)(ws + (4  << 20));          // 4 MB
  __hip_bfloat16* Vb  = (__hip_bfloat16*)(ws + (8  << 20)); // 2 MB
  __hip_bfloat16* Qt  = (__hip_bfloat16*)(ws + (10 << 20)); // 2 MB
  __hip_bfloat16* Kt  = (__hip_bfloat16*)(ws + (12 << 20)); // 2 MB
  float* Ot2          = (float*)(ws + (14 << 20));          // 4 MB (channel-major)
  float* rn           = (float*)(ws + (18 << 20));          // 2 KB

  k_qkv   <<<768,  256, 0, stream>>>(x, y, w_qkv, Qf, Kf, Vb);
  k_norms <<<512,  256, 0, stream>>>(Qf, Kf, rn);
  k_ntr   <<<512,  256, 0, stream>>>(Qf, Kf, rn, Qt, Kt);
  k_attn  <<<1024, 512, 0, stream>>>(Qt, Kt, Vb, Ot2);
  k_proj  <<<256,  256, 0, stream>>>(Ot2, w_out, b_out, out);
}

// Round 7
// 151.217 us; speedup vs baseline: 1.5973x; 1.5973x over previous
//
#include <hip/hip_runtime.h>
#include <hip/hip_bf16.h>

#define HEADS 4
#define DIMH  32
#define HID   128
#define DIM   128
#define NSP   4096
// 10 * log2(e) folded into Qt at k_ntr time; attention uses exp2 directly.
#define QSCALE_LOG2E 14.426950408889634f

typedef __attribute__((ext_vector_type(4)))  float f32x4;
typedef __attribute__((ext_vector_type(16))) float f32x16;
typedef __attribute__((ext_vector_type(8)))  short s16x8;

// ---------------- fused QKV GEMM (fp32 VALU, blockIdx-uniform weights) ----------------
// grid = 24 chunks (16 out-rows each) x 32 col-tiles (256 cols), block 256.
// chunk 0..7 -> Q rows from x; 8..15 -> K rows from y; 16..23 -> V rows from y (bf16).
__global__ __launch_bounds__(256, 4) void k_qkv(const float* __restrict__ x,
                                                const float* __restrict__ y,
                                                const float* __restrict__ w,
                                                float* __restrict__ Qf,
                                                float* __restrict__ Kf,
                                                __hip_bfloat16* __restrict__ Vb) {
  int ct = blockIdx.x & 31, ch = blockIdx.x >> 5;   // ch 0..23
  int g = ct * 256 + threadIdx.x;
  int b = g >> 12, n = g & 4095;
  const float* src = (ch < 8 ? x : y) + (size_t)b * DIM * NSP + n;
  int wrow = (ch < 8 ? ch * 16 : HID + (ch - 8) * 16);
  float acc[16];
#pragma unroll
  for (int i = 0; i < 16; ++i) acc[i] = 0.f;
#pragma unroll 1
  for (int c0 = 0; c0 < DIM; c0 += 32) {
    float cache[32];
#pragma unroll
    for (int cc = 0; cc < 32; ++cc) cache[cc] = src[(size_t)(c0 + cc) * NSP];
#pragma unroll
    for (int cc = 0; cc < 32; ++cc)
#pragma unroll
      for (int i = 0; i < 16; ++i)
        acc[i] += w[(wrow + i) * DIM + c0 + cc] * cache[cc];
  }
  if (ch < 8) {
    float* dst = Qf + (size_t)b * HID * NSP + n;
#pragma unroll
    for (int i = 0; i < 16; ++i) dst[(size_t)(ch * 16 + i) * NSP] = acc[i];
  } else if (ch < 16) {
    float* dst = Kf + (size_t)b * HID * NSP + n;
#pragma unroll
    for (int i = 0; i < 16; ++i) dst[(size_t)((ch - 8) * 16 + i) * NSP] = acc[i];
  } else {
    __hip_bfloat16* dst = Vb + (size_t)b * HID * NSP + n;
#pragma unroll
    for (int i = 0; i < 16; ++i) dst[(size_t)((ch - 16) * 16 + i) * NSP] = __float2bfloat16(acc[i]);
  }
}

// ---------------- row norms (over spatial axis) for Q and K ----------------
__global__ __launch_bounds__(256) void k_norms(const float* __restrict__ Qf,
                                               const float* __restrict__ Kf,
                                               float* __restrict__ rn) {
  int row = blockIdx.x;  // 0..255 Q rows, 256..511 K rows
  const float* src = (row < 256 ? Qf + (size_t)row * NSP : Kf + (size_t)(row - 256) * NSP);
  float ss = 0.f;
  for (int i = threadIdx.x; i < NSP; i += 256) { float v = src[i]; ss += v * v; }
  for (int m = 32; m; m >>= 1) ss += __shfl_xor(ss, m);
  __shared__ float red[4];
  if ((threadIdx.x & 63) == 0) red[threadIdx.x >> 6] = ss;
  __syncthreads();
  if (threadIdx.x == 0) {
    float t = red[0] + red[1] + red[2] + red[3];
    rn[row] = 1.f / fmaxf(sqrtf(t), 1e-12f);
  }
}

// ---------------- normalize + transpose to [b,h,n,32] bf16 (Q gets exp2 scale) ----------------
__global__ __launch_bounds__(256) void k_ntr(const float* __restrict__ Qf,
                                             const float* __restrict__ Kf,
                                             const float* __restrict__ rn,
                                             __hip_bfloat16* __restrict__ Qt,
                                             __hip_bfloat16* __restrict__ Kt) {
  int id   = blockIdx.x;        // 2 tensors * 2 b * 4 h * 32 itiles
  int tens = id >> 8;
  int rem  = id & 255;
  int b = rem >> 7, h = (rem >> 5) & 3, it = rem & 31;
  const float* src = (tens ? Kf : Qf) + ((size_t)(b * HID + h * DIMH)) * NSP + it * 128;
  const float* rns = rn + tens * 256 + b * HID + h * DIMH;
  __hip_bfloat16* dst = (tens ? Kt : Qt) + ((size_t)(b * HEADS + h) * NSP + it * 128) * DIMH;

  __shared__ float tile[DIMH][132];
  int d  = threadIdx.x >> 3;
  int cb = (threadIdx.x & 7) * 16;
  float s = rns[d] * (tens ? 1.f : QSCALE_LOG2E);
#pragma unroll
  for (int k = 0; k < 16; ++k) tile[d][cb + k] = src[(size_t)d * NSP + cb + k] * s;
  __syncthreads();
  int i = threadIdx.x >> 1, dh = (threadIdx.x & 1) * 16;
  unsigned outw[8];
#pragma unroll
  for (int k = 0; k < 8; ++k) {
    __hip_bfloat16 a = __float2bfloat16(tile[dh + 2 * k][i]);
    __hip_bfloat16 c = __float2bfloat16(tile[dh + 2 * k + 1][i]);
    unsigned lo = *(unsigned short*)&a, hi = *(unsigned short*)&c;
    outw[k] = lo | (hi << 16);
  }
  *(uint4*)(dst + i * DIMH + dh)     = *(uint4*)outw;
  *(uint4*)(dst + i * DIMH + dh + 8) = *(uint4*)(outw + 4);
}

// ---------------- flash attention: 32x32x16 MFMA, in-register softmax ----------------
__device__ __forceinline__ unsigned cvtpk_bf16(float a, float b) {
  unsigned d;
  asm("v_cvt_pk_bf16_f32 %0, %1, %2" : "=v"(d) : "v"(a), "v"(b));
  return d;
}

struct K4 { s16x8 k[4]; };
struct V4 { s16x8 v[4]; };

__device__ __forceinline__ K4 ldK(const __hip_bfloat16* kp, int j0) {
  K4 f;
#pragma unroll
  for (int s2 = 0; s2 < 2; ++s2)
#pragma unroll
    for (int kh = 0; kh < 2; ++kh)
      f.k[s2 * 2 + kh] = *(const s16x8*)(kp + (size_t)(j0 + s2 * 32) * DIMH + kh * 16);
  return f;
}
__device__ __forceinline__ V4 ldV(const __hip_bfloat16* vp, int j0) {
  V4 f;
#pragma unroll
  for (int cc = 0; cc < 4; ++cc)
    f.v[cc] = *(const s16x8*)(vp + j0 + cc * 16);
  return f;
}

// One 32(q-rows) x 32(j) subtile: QK^T (2 MFMA), exp2, pack, PV (2 MFMA).
__device__ __forceinline__ void attn_sub(s16x8 k0, s16x8 k1, s16x8 v0, s16x8 v1,
                                         const s16x8* qb, f32x16& O, float& lsum) {
  f32x16 z = {};
  f32x16 s = __builtin_amdgcn_mfma_f32_32x32x16_bf16(k0, qb[0], z, 0, 0, 0);
  s        = __builtin_amdgcn_mfma_f32_32x32x16_bf16(k1, qb[1], s, 0, 0, 0);
  float p[16];
#pragma unroll
  for (int r = 0; r < 16; ++r) p[r] = __builtin_amdgcn_exp2f(s[r]);
  float t0 = 0.f, t1 = 0.f;
#pragma unroll
  for (int r = 0; r < 16; r += 2) { t0 += p[r]; t1 += p[r + 1]; }
  lsum += t0 + t1;
  unsigned wA[4], wB[4];
#pragma unroll
  for (int m = 0; m < 4; ++m) {
    wA[m] = cvtpk_bf16(p[4 * m], p[4 * m + 1]);
    wB[m] = cvtpk_bf16(p[4 * m + 2], p[4 * m + 3]);
  }
#define PV_CHUNK(c, vfrag)                                                     \
  {                                                                            \
    unsigned a0 = wA[2 * (c)], a1 = wA[2 * (c) + 1];                           \
    unsigned b0 = wB[2 * (c)], b1 = wB[2 * (c) + 1];                           \
    asm("v_permlane32_swap_b32 %0, %1" : "+v"(a0), "+v"(a1));                  \
    asm("v_permlane32_swap_b32 %0, %1" : "+v"(b0), "+v"(b1));                  \
    union { unsigned u[4]; s16x8 v; } pa;                                      \
    pa.u[0] = a0; pa.u[1] = b0; pa.u[2] = a1; pa.u[3] = b1;                    \
    O = __builtin_amdgcn_mfma_f32_32x32x16_bf16(pa.v, vfrag, O, 0, 0, 0);      \
  }
  PV_CHUNK(0, v0);
  PV_CHUNK(1, v1);
#undef PV_CHUNK
}

// block = 8 waves (one 32-row q-tile, 8-way j split), grid = 8 bh * 128 rtiles.
// launch_bounds(512,4): VGPR cap 128 -> prefetch fits in regs, NO spill (R6 lesson:
// (512,8) forced <=64 VGPR and spilled 380 MB to scratch).
// Output written channel-major: Ot2[(bh*32+d)*NSP + n] via LDS transpose.
__global__ __launch_bounds__(512, 4) void k_attn(const __hip_bfloat16* __restrict__ Qt,
                                                 const __hip_bfloat16* __restrict__ Kt,
                                                 const __hip_bfloat16* __restrict__ Vb,
                                                 float* __restrict__ Ot2) {
  int bid = blockIdx.x;
  int swz = (bid & 7) * 128 + (bid >> 3);   // 1024 blocks, XCD-contiguous
  int bh = swz >> 7, rt = swz & 127;
  int tid = threadIdx.x, lane = tid & 63, wave = tid >> 6;  // wave = j-eighth
  int l31 = lane & 31, hi = lane >> 5;
  int i0 = rt * 32;

  const __hip_bfloat16* kp = Kt + ((size_t)bh * NSP + l31) * DIMH + hi * 8;
  const __hip_bfloat16* vp = Vb + ((size_t)bh * DIMH + l31) * NSP + hi * 8;
  const __hip_bfloat16* qp = Qt + ((size_t)bh * NSP + i0 + l31) * DIMH + hi * 8;
  s16x8 qb[2] = { *(const s16x8*)qp, *(const s16x8*)(qp + 16) };

  f32x16 O = {};
  float ls0 = 0.f, ls1 = 0.f;
  int jbase = wave * 512;

  // one-step software prefetch in named registers (fits under the 128-VGPR cap)
  K4 kc = ldK(kp, jbase);
  V4 vc = ldV(vp, jbase);
#pragma unroll 1
  for (int t = 0; t < 7; ++t) {
    K4 kn = ldK(kp, jbase + (t + 1) * 64);
    V4 vn = ldV(vp, jbase + (t + 1) * 64);
    attn_sub(kc.k[0], kc.k[1], vc.v[0], vc.v[1], qb, O, ls0);
    attn_sub(kc.k[2], kc.k[3], vc.v[2], vc.v[3], qb, O, ls1);
    kc = kn; vc = vn;
  }
  attn_sub(kc.k[0], kc.k[1], vc.v[0], vc.v[1], qb, O, ls0);
  attn_sub(kc.k[2], kc.k[3], vc.v[2], vc.v[3], qb, O, ls1);
  float lsum = ls0 + ls1;

  // ---- merge 8 j-eighths, divide by row sums, transpose to channel-major ----
  __shared__ float Olds[7][16][68];
  __shared__ float Llds[8][64];
  float lw = lsum + __shfl_xor(lsum, 32);   // per-row sum (row = l31)
  if (wave) {
#pragma unroll
    for (int r = 0; r < 16; ++r) Olds[wave - 1][r][lane] = O[r];
    Llds[wave][lane] = lw;
  }
  __syncthreads();
  if (wave == 0) {
    float ltot = lw;
#pragma unroll
    for (int w2 = 1; w2 < 8; ++w2) ltot += Llds[w2][lane];
    if (hi == 0) Llds[0][l31] = ltot;       // reindex by row (same-wave DS order)
#pragma unroll
    for (int r = 0; r < 16; ++r) {
      int i = (r & 3) + 8 * (r >> 2) + 4 * hi;
      float li = Llds[0][i];
      float sum = O[r];
#pragma unroll
      for (int w2 = 0; w2 < 7; ++w2) sum += Olds[w2][r][lane];
      Olds[0][r][lane] = sum / li;
    }
  }
  __syncthreads();
  // store: 32 d x 32 n; lanes cover n (coalesced 128B per d-row); 512 thr -> 2 d each
  {
    int n = tid & 31, dgrp = tid >> 5;       // dgrp 0..15, 2 d each
    int r = (n & 3) | ((n >> 3) << 2);
    int h2 = (n >> 2) & 1;
    float* obase = Ot2 + ((size_t)bh * DIMH) * NSP + i0 + n;
#pragma unroll
    for (int k2 = 0; k2 < 2; ++k2) {
      int d = dgrp * 2 + k2;
      obase[(size_t)d * NSP] = Olds[0][r][h2 * 32 + d];
    }
  }
}

// ---------------- output projection: channel GEMM over Ot2 ----------------
// grid = 8 chunks (16 outs) x 32 ct, block 256.
__global__ __launch_bounds__(256, 4) void k_proj(const float* __restrict__ Ot2,
                                                 const float* __restrict__ w,
                                                 const float* __restrict__ bias,
                                                 float* __restrict__ out) {
  int ct = blockIdx.x & 31, oc = blockIdx.x >> 5;   // oc 0..7
  int g = ct * 256 + threadIdx.x;
  int b = g >> 12, n = g & 4095;
  const float* op = Ot2 + (size_t)b * HID * NSP + n;
  float acc[16];
#pragma unroll
  for (int i = 0; i < 16; ++i) acc[i] = bias[oc * 16 + i];
#pragma unroll 1
  for (int c0 = 0; c0 < HID; c0 += 32) {
    float cache[32];
#pragma unroll
    for (int cc = 0; cc < 32; ++cc) cache[cc] = op[(size_t)(c0 + cc) * NSP];
#pragma unroll
    for (int cc = 0; cc < 32; ++cc)
#pragma unroll
      for (int i = 0; i < 16; ++i)
        acc[i] += w[(oc * 16 + i) * HID + c0 + cc] * cache[cc];
  }
  float* outb = out + (size_t)b * DIM * NSP + n;
#pragma unroll
  for (int i = 0; i < 16; ++i) outb[(size_t)(oc * 16 + i) * NSP] = acc[i];
}

extern "C" void kernel_launch(void* const* d_in, const int* in_sizes, int n_in,
                              void* d_out, int out_size, void* d_ws, size_t ws_size,
                              hipStream_t stream) {
  const float* x     = (const float*)d_in[0];
  const float* y     = (const float*)d_in[1];
  const float* w_qkv = (const float*)d_in[2];
  const float* w_out = (const float*)d_in[3];
  const float* b_out = (const float*)d_in[4];
  float* out = (float*)d_out;

  char* ws = (char*)d_ws;
  float* Qf           = (float*)(ws);                       // 4 MB
  float* Kf           = (float*)(ws + (4  << 20));          // 4 MB
  __hip_bfloat16* Vb  = (__hip_bfloat16*)(ws + (8  << 20)); // 2 MB
  __hip_bfloat16* Qt  = (__hip_bfloat16*)(ws + (10 << 20)); // 2 MB
  __hip_bfloat16* Kt  = (__hip_bfloat16*)(ws + (12 << 20)); // 2 MB
  float* Ot2          = (float*)(ws + (14 << 20));          // 4 MB (channel-major)
  float* rn           = (float*)(ws + (18 << 20));          // 2 KB

  k_qkv   <<<768,  256, 0, stream>>>(x, y, w_qkv, Qf, Kf, Vb);
  k_norms <<<512,  256, 0, stream>>>(Qf, Kf, rn);
  k_ntr   <<<512,  256, 0, stream>>>(Qf, Kf, rn, Qt, Kt);
  k_attn  <<<1024, 512, 0, stream>>>(Qt, Kt, Vb, Ot2);
  k_proj  <<<256,  256, 0, stream>>>(Ot2, w_out, b_out, out);
}

// Round 8
// 122.113 us; speedup vs baseline: 1.9780x; 1.2383x over previous
//
#include <hip/hip_runtime.h>
#include <hip/hip_bf16.h>

#define HEADS 4
#define DIMH  32
#define HID   128
#define DIM   128
#define NSP   4096
// 10 * log2(e) folded into Qt at k_ntr time; attention uses exp2 directly.
#define QSCALE_LOG2E 14.426950408889634f

typedef __attribute__((ext_vector_type(4)))  float f32x4;
typedef __attribute__((ext_vector_type(16))) float f32x16;
typedef __attribute__((ext_vector_type(8)))  short s16x8;

// ---------------- fused QKV GEMM (fp32 VALU, blockIdx-uniform weights) ----------------
// grid = 768: xcd-localized columns (each XCD's L2 holds a 1024-col slice of x,y).
// chunk 0..7 -> Q rows from x; 8..15 -> K rows from y; 16..23 -> V rows from y (bf16).
__global__ __launch_bounds__(256, 4) void k_qkv(const float* __restrict__ x,
                                                const float* __restrict__ y,
                                                const float* __restrict__ w,
                                                float* __restrict__ Qf,
                                                float* __restrict__ Kf,
                                                __hip_bfloat16* __restrict__ Vb) {
  int xcd = blockIdx.x & 7;
  int idx = blockIdx.x >> 3;          // 0..95
  int ct  = xcd * 4 + (idx & 3);      // col-tile 0..31 (XCD-localized)
  int ch  = idx >> 2;                 // 0..23
  int g = ct * 256 + threadIdx.x;
  int b = g >> 12, n = g & 4095;
  const float* src = (ch < 8 ? x : y) + (size_t)b * DIM * NSP + n;
  int wrow = (ch < 8 ? ch * 16 : HID + (ch - 8) * 16);
  float acc[16];
#pragma unroll
  for (int i = 0; i < 16; ++i) acc[i] = 0.f;
#pragma unroll 1
  for (int c0 = 0; c0 < DIM; c0 += 32) {
    float cache[32];
#pragma unroll
    for (int cc = 0; cc < 32; ++cc) cache[cc] = src[(size_t)(c0 + cc) * NSP];
#pragma unroll
    for (int cc = 0; cc < 32; ++cc)
#pragma unroll
      for (int i = 0; i < 16; ++i)
        acc[i] += w[(wrow + i) * DIM + c0 + cc] * cache[cc];
  }
  if (ch < 8) {
    float* dst = Qf + (size_t)b * HID * NSP + n;
#pragma unroll
    for (int i = 0; i < 16; ++i) dst[(size_t)(ch * 16 + i) * NSP] = acc[i];
  } else if (ch < 16) {
    float* dst = Kf + (size_t)b * HID * NSP + n;
#pragma unroll
    for (int i = 0; i < 16; ++i) dst[(size_t)((ch - 8) * 16 + i) * NSP] = acc[i];
  } else {
    __hip_bfloat16* dst = Vb + (size_t)b * HID * NSP + n;
#pragma unroll
    for (int i = 0; i < 16; ++i) dst[(size_t)((ch - 16) * 16 + i) * NSP] = __float2bfloat16(acc[i]);
  }
}

// ---------------- row norms (over spatial axis) for Q and K ----------------
__global__ __launch_bounds__(256) void k_norms(const float* __restrict__ Qf,
                                               const float* __restrict__ Kf,
                                               float* __restrict__ rn) {
  int row = blockIdx.x;  // 0..255 Q rows, 256..511 K rows
  const float* src = (row < 256 ? Qf + (size_t)row * NSP : Kf + (size_t)(row - 256) * NSP);
  float ss = 0.f;
  for (int i = threadIdx.x; i < NSP; i += 256) { float v = src[i]; ss += v * v; }
  for (int m = 32; m; m >>= 1) ss += __shfl_xor(ss, m);
  __shared__ float red[4];
  if ((threadIdx.x & 63) == 0) red[threadIdx.x >> 6] = ss;
  __syncthreads();
  if (threadIdx.x == 0) {
    float t = red[0] + red[1] + red[2] + red[3];
    rn[row] = 1.f / fmaxf(sqrtf(t), 1e-12f);
  }
}

// ---------------- normalize + transpose to [b,h,n,32] bf16 (Q gets exp2 scale) ----------------
__global__ __launch_bounds__(256) void k_ntr(const float* __restrict__ Qf,
                                             const float* __restrict__ Kf,
                                             const float* __restrict__ rn,
                                             __hip_bfloat16* __restrict__ Qt,
                                             __hip_bfloat16* __restrict__ Kt) {
  int id   = blockIdx.x;        // 2 tensors * 2 b * 4 h * 32 itiles
  int tens = id >> 8;
  int rem  = id & 255;
  int b = rem >> 7, h = (rem >> 5) & 3, it = rem & 31;
  const float* src = (tens ? Kf : Qf) + ((size_t)(b * HID + h * DIMH)) * NSP + it * 128;
  const float* rns = rn + tens * 256 + b * HID + h * DIMH;
  __hip_bfloat16* dst = (tens ? Kt : Qt) + ((size_t)(b * HEADS + h) * NSP + it * 128) * DIMH;

  __shared__ float tile[DIMH][132];
  int d  = threadIdx.x >> 3;
  int cb = (threadIdx.x & 7) * 16;
  float s = rns[d] * (tens ? 1.f : QSCALE_LOG2E);
#pragma unroll
  for (int k = 0; k < 16; ++k) tile[d][cb + k] = src[(size_t)d * NSP + cb + k] * s;
  __syncthreads();
  int i = threadIdx.x >> 1, dh = (threadIdx.x & 1) * 16;
  unsigned outw[8];
#pragma unroll
  for (int k = 0; k < 8; ++k) {
    __hip_bfloat16 a = __float2bfloat16(tile[dh + 2 * k][i]);
    __hip_bfloat16 c = __float2bfloat16(tile[dh + 2 * k + 1][i]);
    unsigned lo = *(unsigned short*)&a, hi = *(unsigned short*)&c;
    outw[k] = lo | (hi << 16);
  }
  *(uint4*)(dst + i * DIMH + dh)     = *(uint4*)outw;
  *(uint4*)(dst + i * DIMH + dh + 8) = *(uint4*)(outw + 4);
}

// ---------------- flash attention: LDS-staged K/V, 32x32x16 MFMA, in-reg softmax ----------------
__device__ __forceinline__ unsigned cvtpk_bf16(float a, float b) {
  unsigned d;
  asm("v_cvt_pk_bf16_f32 %0, %1, %2" : "=v"(d) : "v"(a), "v"(b));
  return d;
}

__device__ __forceinline__ void glds16(const __hip_bfloat16* g, __hip_bfloat16* l) {
  __builtin_amdgcn_global_load_lds(
      (const __attribute__((address_space(1))) unsigned int*)(const void*)g,
      (__attribute__((address_space(3))) unsigned int*)(void*)l, 16, 0, 0);
}

// One 32(q-rows) x 32(j) subtile from LDS tiles (XOR-swizzled layout).
__device__ __forceinline__ void attn_sub2(const __hip_bfloat16* kbase,
                                          const __hip_bfloat16* vbase,
                                          int s, int l31, int hi,
                                          s16x8 qb0, s16x8 qb1,
                                          f32x16& O, float& lsum) {
  int krx = l31 & 3, vrx = l31 & 7;
  const __hip_bfloat16* krow = kbase + (s * 32 + l31) * DIMH;
  // chunk c = kh*2+hi, stored at slot c ^ (row&3)
  s16x8 kf0 = *(const s16x8*)(krow + (((hi) ^ krx) << 3));
  s16x8 kf1 = *(const s16x8*)(krow + (((2 + hi) ^ krx) << 3));
  f32x16 z = {};
  f32x16 sv = __builtin_amdgcn_mfma_f32_32x32x16_bf16(kf0, qb0, z, 0, 0, 0);
  sv        = __builtin_amdgcn_mfma_f32_32x32x16_bf16(kf1, qb1, sv, 0, 0, 0);
  float p[16];
#pragma unroll
  for (int r = 0; r < 16; ++r) p[r] = __builtin_amdgcn_exp2f(sv[r]);
  float t0 = 0.f, t1 = 0.f;
#pragma unroll
  for (int r = 0; r < 16; r += 2) { t0 += p[r]; t1 += p[r + 1]; }
  lsum += t0 + t1;
  unsigned wA[4], wB[4];
#pragma unroll
  for (int m = 0; m < 4; ++m) {
    wA[m] = cvtpk_bf16(p[4 * m], p[4 * m + 1]);
    wB[m] = cvtpk_bf16(p[4 * m + 2], p[4 * m + 3]);
  }
  const __hip_bfloat16* vrow = vbase + l31 * 64;
#define PV_CHUNK(c2, vfrag)                                                    \
  {                                                                            \
    unsigned a0 = wA[2 * (c2)], a1 = wA[2 * (c2) + 1];                         \
    unsigned b0 = wB[2 * (c2)], b1 = wB[2 * (c2) + 1];                         \
    asm("v_permlane32_swap_b32 %0, %1" : "+v"(a0), "+v"(a1));                  \
    asm("v_permlane32_swap_b32 %0, %1" : "+v"(b0), "+v"(b1));                  \
    union { unsigned u[4]; s16x8 v; } pa;                                      \
    pa.u[0] = a0; pa.u[1] = b0; pa.u[2] = a1; pa.u[3] = b1;                    \
    O = __builtin_amdgcn_mfma_f32_32x32x16_bf16(pa.v, vfrag, O, 0, 0, 0);      \
  }
#pragma unroll
  for (int c2 = 0; c2 < 2; ++c2) {
    int cc = s * 2 + c2;                 // 16-j chunk within 64-j tile
    s16x8 vf = *(const s16x8*)(vrow + (((cc * 2 + hi) ^ vrx) << 3));
    PV_CHUNK(c2, vf);
  }
#undef PV_CHUNK
}

// grid = 256 blocks (bh = bid&7 -> XCD-local K/V), 1024 threads = 16 waves:
// wave = (qsub 0..3) x (jq 0..3); block covers 128 q-rows x full 4096 j.
// K/V double-buffered in LDS via global_load_lds with XOR-swizzled source.
__global__ __launch_bounds__(1024, 4) void k_attn(const __hip_bfloat16* __restrict__ Qt,
                                                  const __hip_bfloat16* __restrict__ Kt,
                                                  const __hip_bfloat16* __restrict__ Vb,
                                                  float* __restrict__ Ot2) {
  int bh = blockIdx.x & 7, qt = blockIdx.x >> 3;   // 8 bh x 32 qt
  int tid = threadIdx.x, lane = tid & 63, wave = tid >> 6;
  int qsub = wave & 3, jq = wave >> 2;
  int l31 = lane & 31, hi = lane >> 5;
  int i0 = qt * 128 + qsub * 32;
  int jbase = jq * 1024;

  __shared__ alignas(16) __hip_bfloat16 Ks[4][2][2048];  // [jq][buf][64 rows x 32 d] 32 KB
  __shared__ alignas(16) __hip_bfloat16 Vs[4][2][2048];  // [jq][buf][32 d x 64 j]   32 KB
  __shared__ float Olds[4][3][16][68];                   // 52 KB
  __shared__ float Llds[16][64];                         // 4 KB

  const __hip_bfloat16* kg = Kt + (size_t)bh * NSP * DIMH;  // [n][32]
  const __hip_bfloat16* vg = Vb + (size_t)bh * DIMH * NSP;  // [d][n]
  const __hip_bfloat16* qp = Qt + ((size_t)bh * NSP + i0 + l31) * DIMH + hi * 8;
  s16x8 qb0 = *(const s16x8*)qp;
  s16x8 qb1 = *(const s16x8*)(qp + 16);

  // stager: unit u = qsub*64+lane; LDS linear at u*16B; global source pre-swizzled
  int ku = qsub * 64 + lane;
  int krow = ku >> 2;
  int kchunk = (ku & 3) ^ (krow & 3);
  const __hip_bfloat16* ksrc0 = kg + (size_t)krow * DIMH + (kchunk << 3);
  int vd = ku >> 3;
  int vchunk = (ku & 7) ^ (vd & 7);
  const __hip_bfloat16* vsrc0 = vg + (size_t)vd * NSP + (vchunk << 3);
  int lbase = qsub * 512;   // elems within Ks/Vs[jq][buf]

  f32x16 O = {};
  float ls0 = 0.f, ls1 = 0.f;

  // prologue: stage tile 0
  glds16(ksrc0 + (size_t)jbase * DIMH, &Ks[jq][0][lbase]);
  glds16(vsrc0 + jbase,                &Vs[jq][0][lbase]);
  asm volatile("s_waitcnt vmcnt(0)" ::: "memory");
  __syncthreads();

#pragma unroll 1
  for (int t = 0; t < 16; ++t) {
    int buf = t & 1;
    if (t < 15) {
      int j1 = jbase + (t + 1) * 64;
      glds16(ksrc0 + (size_t)j1 * DIMH, &Ks[jq][buf ^ 1][lbase]);
      glds16(vsrc0 + j1,                &Vs[jq][buf ^ 1][lbase]);
    }
    const __hip_bfloat16* kbase = &Ks[jq][buf][0];
    const __hip_bfloat16* vbase = &Vs[jq][buf][0];
    attn_sub2(kbase, vbase, 0, l31, hi, qb0, qb1, O, ls0);
    attn_sub2(kbase, vbase, 1, l31, hi, qb0, qb1, O, ls1);
    if (t < 15) {
      asm volatile("s_waitcnt vmcnt(0)" ::: "memory");
      __syncthreads();
    }
  }

  // ---- merge 4 j-quarters, divide by row sums, write channel-major ----
  float lsum = ls0 + ls1;
  float lw = lsum + __shfl_xor(lsum, 32);   // full row sum for q-row i = l31 (this jq)
  if (jq) {
#pragma unroll
    for (int r = 0; r < 16; ++r) Olds[qsub][jq - 1][r][lane] = O[r];
  }
  Llds[wave][lane] = lw;
  __syncthreads();
  if (jq == 0) {
    float ltot = lw + Llds[wave + 4][lane] + Llds[wave + 8][lane] + Llds[wave + 12][lane];
    if (hi == 0) Llds[wave][l31] = ltot;    // reindex by q-row (same-wave DS order)
#pragma unroll
    for (int r = 0; r < 16; ++r) {
      int i = (r & 3) + 8 * (r >> 2) + 4 * hi;
      float li = Llds[wave][i];
      float sum = O[r] + Olds[qsub][0][r][lane] + Olds[qsub][1][r][lane] + Olds[qsub][2][r][lane];
      Olds[qsub][0][r][lane] = sum / li;
    }
  }
  __syncthreads();
  // store: per qsub a 32d x 32n tile; 1024 threads -> 4 floats each, coalesced per d-row
  {
    int n = tid & 31, dgrp = (tid >> 5) & 7, q2 = tid >> 8;
    int r = (n & 3) | ((n >> 3) << 2);
    int h2 = (n >> 2) & 1;
    float* obase = Ot2 + (size_t)bh * DIMH * NSP + qt * 128 + q2 * 32 + n;
#pragma unroll
    for (int k2 = 0; k2 < 4; ++k2) {
      int d = dgrp * 4 + k2;
      obase[(size_t)d * NSP] = Olds[q2][0][r][h2 * 32 + d];
    }
  }
}

// ---------------- output projection: channel GEMM over Ot2, XCD-localized cols ----------------
__global__ __launch_bounds__(256, 4) void k_proj(const float* __restrict__ Ot2,
                                                 const float* __restrict__ w,
                                                 const float* __restrict__ bias,
                                                 float* __restrict__ out) {
  int xcd = blockIdx.x & 7;
  int idx = blockIdx.x >> 3;          // 0..31
  int ct  = xcd * 4 + (idx & 3);      // col-tile 0..31 (XCD-localized)
  int oc  = idx >> 2;                 // 0..7
  int g = ct * 256 + threadIdx.x;
  int b = g >> 12, n = g & 4095;
  const float* op = Ot2 + (size_t)b * HID * NSP + n;
  float acc[16];
#pragma unroll
  for (int i = 0; i < 16; ++i) acc[i] = bias[oc * 16 + i];
#pragma unroll 1
  for (int c0 = 0; c0 < HID; c0 += 32) {
    float cache[32];
#pragma unroll
    for (int cc = 0; cc < 32; ++cc) cache[cc] = op[(size_t)(c0 + cc) * NSP];
#pragma unroll
    for (int cc = 0; cc < 32; ++cc)
#pragma unroll
      for (int i = 0; i < 16; ++i)
        acc[i] += w[(oc * 16 + i) * HID + c0 + cc] * cache[cc];
  }
  float* outb = out + (size_t)b * DIM * NSP + n;
#pragma unroll
  for (int i = 0; i < 16; ++i) outb[(size_t)(oc * 16 + i) * NSP] = acc[i];
}

extern "C" void kernel_launch(void* const* d_in, const int* in_sizes, int n_in,
                              void* d_out, int out_size, void* d_ws, size_t ws_size,
                              hipStream_t stream) {
  const float* x     = (const float*)d_in[0];
  const float* y     = (const float*)d_in[1];
  const float* w_qkv = (const float*)d_in[2];
  const float* w_out = (const float*)d_in[3];
  const float* b_out = (const float*)d_in[4];
  float* out = (float*)d_out;

  char* ws = (char*)d_ws;
  float* Qf           = (float*)(ws);                       // 4 MB
  float* Kf           = (float*)(ws + (4  << 20));          // 4 MB
  __hip_bfloat16* Vb  = (__hip_bfloat16*)(ws + (8  << 20)); // 2 MB
  __hip_bfloat16* Qt  = (__hip_bfloat16*)(ws + (10 << 20)); // 2 MB
  __hip_bfloat16* Kt  = (__hip_bfloat16*)(ws + (12 << 20)); // 2 MB
  float* Ot2          = (float*)(ws + (14 << 20));          // 4 MB (channel-major)
  float* rn           = (float*)(ws + (18 << 20));          // 2 KB

  k_qkv   <<<768,  256,  0, stream>>>(x, y, w_qkv, Qf, Kf, Vb);
  k_norms <<<512,  256,  0, stream>>>(Qf, Kf, rn);
  k_ntr   <<<512,  256,  0, stream>>>(Qf, Kf, rn, Qt, Kt);
  k_attn  <<<256,  1024, 0, stream>>>(Qt, Kt, Vb, Ot2);
  k_proj  <<<256,  256,  0, stream>>>(Ot2, w_out, b_out, out);
}

// Round 10
// 79.102 us; speedup vs baseline: 3.0535x; 1.5437x over previous
//
#include <hip/hip_runtime.h>
#include <hip/hip_bf16.h>

#define HEADS 4
#define DIMH  32
#define HID   128
#define DIM   128
#define NSP   4096
// 10 * log2(e) folded into Q at k_scale time; attention uses exp2 directly.
#define QSCALE_LOG2E 14.426950408889634f

typedef __attribute__((ext_vector_type(4)))  float f32x4;
typedef __attribute__((ext_vector_type(16))) float f32x16;
typedef __attribute__((ext_vector_type(8)))  short s16x8;

__device__ __forceinline__ unsigned cvtpk_bf16(float a, float b) {
  unsigned d;
  asm("v_cvt_pk_bf16_f32 %0, %1, %2" : "=v"(d) : "v"(a), "v"(b));
  return d;
}
__device__ __forceinline__ float bf2f(short s) {
  union { unsigned u; float f; } c;
  c.u = ((unsigned)(unsigned short)s) << 16;
  return c.f;
}

// ---------------- convert+transpose x,y fp32 [b][c][n] -> bf16 [b*n][c] ----------------
__global__ __launch_bounds__(256) void k_cvt(const float* __restrict__ x,
                                             const float* __restrict__ y,
                                             __hip_bfloat16* __restrict__ xt,
                                             __hip_bfloat16* __restrict__ yt) {
  int bid = blockIdx.x;          // 2 tensor * 2 b * 64 ntiles
  int t = bid >> 7, rem = bid & 127;
  int b = rem >> 6, nt = rem & 63;
  int n0 = nt * 64;
  const float* src = (t ? y : x) + (size_t)b * DIM * NSP;
  __hip_bfloat16* dst = (t ? yt : xt) + (size_t)b * NSP * DIM;

  __shared__ alignas(16) __hip_bfloat16 tile[64 * 136];
  int c = threadIdx.x >> 1, nh = (threadIdx.x & 1) * 32;
  const float* sp = src + (size_t)c * NSP + n0 + nh;
#pragma unroll
  for (int i = 0; i < 32; ++i)
    tile[(nh + i) * 136 + c] = __float2bfloat16(sp[i]);
  __syncthreads();
  int rrow = threadIdx.x >> 2, cb = (threadIdx.x & 3) * 32;
  __hip_bfloat16* op = dst + (size_t)(n0 + rrow) * DIM + cb;
  const __hip_bfloat16* ip = tile + rrow * 136 + cb;
#pragma unroll
  for (int k = 0; k < 4; ++k)
    *(s16x8*)(op + k * 8) = *(const s16x8*)(ip + k * 8);
}

// ---------------- QKV GEMM on MFMA: D[orow][n] = sum_c W[orow][c] * src[n][c] ----------------
// orows 0..127 = Q (from xt), 128..255 = K (from yt), 256..383 = V (from yt).
// Writes Qr/Kr bf16 [bh][n][32] (unnormalized), Vb bf16 [bh][d][n].
// Sum-of-squares: deterministic per-wave partials into ssp[512][64] (no atomics).
__global__ __launch_bounds__(256, 4) void k_qkvm(const __hip_bfloat16* __restrict__ xt,
                                                 const __hip_bfloat16* __restrict__ yt,
                                                 const float* __restrict__ w,
                                                 float* __restrict__ ssp,
                                                 __hip_bfloat16* __restrict__ Qr,
                                                 __hip_bfloat16* __restrict__ Kr,
                                                 __hip_bfloat16* __restrict__ Vb) {
  int xcd = blockIdx.x & 7;
  int r = blockIdx.x >> 3;        // 0..47
  int ot = r >> 2;                // 0..11
  int nts = r & 3;
  int tile = xcd * 4 + nts;       // n-tile 0..31
  int n0 = tile * 256;            // global n base (0..8191)
  int lane = threadIdx.x & 63, wave = threadIdx.x >> 6;
  int l31 = lane & 31, hi = lane >> 5;
  int orow = ot * 32 + l31;

  // A-fragments: W row `orow`, bf16; step k covers c = k*16 + hi*8 + 0..7
  s16x8 wf[8];
  const float* wr = w + orow * DIM + hi * 8;
#pragma unroll
  for (int k = 0; k < 8; ++k) {
    f32x4 a = *(const f32x4*)(wr + k * 16);
    f32x4 b2 = *(const f32x4*)(wr + k * 16 + 4);
    union { unsigned u[4]; s16x8 v; } p;
    p.u[0] = cvtpk_bf16(a[0], a[1]);
    p.u[1] = cvtpk_bf16(a[2], a[3]);
    p.u[2] = cvtpk_bf16(b2[0], b2[1]);
    p.u[3] = cvtpk_bf16(b2[2], b2[3]);
    wf[k] = p.v;
  }

  const __hip_bfloat16* src = (ot < 4 ? xt : yt);
  int nw = n0 + wave * 64;
  f32x16 acc0 = {}, acc1 = {};
#pragma unroll
  for (int k = 0; k < 8; ++k) {
    s16x8 b0 = *(const s16x8*)(src + (size_t)(nw + l31) * DIM + k * 16 + hi * 8);
    s16x8 b1 = *(const s16x8*)(src + (size_t)(nw + 32 + l31) * DIM + k * 16 + hi * 8);
    acc0 = __builtin_amdgcn_mfma_f32_32x32x16_bf16(wf[k], b0, acc0, 0, 0, 0);
    acc1 = __builtin_amdgcn_mfma_f32_32x32x16_bf16(wf[k], b1, acc1, 0, 0, 0);
  }

  int b = nw >> 12;               // batch (256-n tiles never straddle)
  if (ot < 8) {
    // Q or K: [bh][n][32] — lane owns col n, regs give d = 8m+4hi+(r&3)
    __hip_bfloat16* dst = (ot < 4 ? Qr : Kr);
    int h = ot & 3;
#pragma unroll
    for (int nt = 0; nt < 2; ++nt) {
      int n = nw + nt * 32 + l31;
      int np = n & 4095;
      __hip_bfloat16* base = dst + ((size_t)((b * HEADS + h) * NSP + np)) * DIMH;
      const f32x16& A = nt ? acc1 : acc0;
#pragma unroll
      for (int m = 0; m < 4; ++m) {
        unsigned u0 = cvtpk_bf16(A[4 * m], A[4 * m + 1]);
        unsigned u1 = cvtpk_bf16(A[4 * m + 2], A[4 * m + 3]);
        uint2 p2; p2.x = u0; p2.y = u1;
        *(uint2*)(base + 8 * m + 4 * hi) = p2;
      }
    }
    // ---- sum-of-squares partials: one slot per (row, tile-in-batch, wave) ----
    float p[16];
#pragma unroll
    for (int r2 = 0; r2 < 16; ++r2) p[r2] = acc0[r2] * acc0[r2] + acc1[r2] * acc1[r2];
#pragma unroll
    for (int r2 = 0; r2 < 16; ++r2) {
#pragma unroll
      for (int m2 = 1; m2 < 32; m2 <<= 1) p[r2] += __shfl_xor(p[r2], m2);
    }
    if (l31 == 0) {
      int t = (ot < 4 ? 0 : 1);
      int widx = (tile & 15) * 4 + wave;              // 0..63
      int rbase = (t * 2 + b) * 128 + h * 32;
#pragma unroll
      for (int r2 = 0; r2 < 16; ++r2) {
        int row = (r2 & 3) + 8 * (r2 >> 2) + 4 * hi;
        ssp[(size_t)(rbase + row) * 64 + widx] = p[r2];
      }
    }
  } else {
    // V: [bh][d][n]
    int h = ot - 8;
#pragma unroll
    for (int nt = 0; nt < 2; ++nt) {
      int n = nw + nt * 32 + l31;
      int np = n & 4095;
      const f32x16& A = nt ? acc1 : acc0;
#pragma unroll
      for (int r2 = 0; r2 < 16; ++r2) {
        int d = (r2 & 3) + 8 * (r2 >> 2) + 4 * hi;
        Vb[((size_t)((b * HEADS + h) * DIMH + d)) * NSP + np] = __float2bfloat16(A[r2]);
      }
    }
  }
}

// ---------------- reduce partials, apply norm scales in place (Q gets exp2 fold) ----------------
__global__ __launch_bounds__(256) void k_scale(const float* __restrict__ ssp,
                                               __hip_bfloat16* __restrict__ Qr,
                                               __hip_bfloat16* __restrict__ Kr) {
  int bid = blockIdx.x;           // 2t * 8bh * 16ns
  int t = bid >> 7, bh = (bid >> 4) & 7, ns = bid & 15;
  __shared__ float sc[32];
  if (threadIdx.x < 32) {
    int b = bh >> 2, h = bh & 3;
    const float* pp = ssp + (size_t)((t * 2 + b) * 128 + h * 32 + (int)threadIdx.x) * 64;
    float s2 = 0.f;
#pragma unroll
    for (int j = 0; j < 64; ++j) s2 += pp[j];
    // eps=0.1 is inert here (row norms ~64); diagnostic guard vs broken ss
    float v = 1.f / fmaxf(sqrtf(s2), 0.1f);
    sc[threadIdx.x] = (t == 0) ? v * QSCALE_LOG2E : v;
  }
  __syncthreads();
  __hip_bfloat16* base = (t ? Kr : Qr) + (size_t)bh * NSP * DIMH;
  int dc = (threadIdx.x & 3) * 8;
  float s0[8];
#pragma unroll
  for (int i = 0; i < 8; ++i) s0[i] = sc[dc + i];
#pragma unroll
  for (int it = 0; it < 4; ++it) {
    int n = ns * 256 + (threadIdx.x >> 2) + it * 64;
    __hip_bfloat16* p = base + (size_t)n * DIMH + dc;
    s16x8 v = *(const s16x8*)p;
    union { unsigned u[4]; s16x8 v; } o;
#pragma unroll
    for (int i2 = 0; i2 < 4; ++i2) {
      float lo = bf2f(v[2 * i2])     * s0[2 * i2];
      float h2 = bf2f(v[2 * i2 + 1]) * s0[2 * i2 + 1];
      o.u[i2] = cvtpk_bf16(lo, h2);
    }
    *(s16x8*)p = o.v;
  }
}

// ---------------- flash attention: LDS-staged K/V, 32x32x16 MFMA, in-reg softmax ----------------
__device__ __forceinline__ void glds16(const __hip_bfloat16* g, __hip_bfloat16* l) {
  __builtin_amdgcn_global_load_lds(
      (const __attribute__((address_space(1))) unsigned int*)(const void*)g,
      (__attribute__((address_space(3))) unsigned int*)(void*)l, 16, 0, 0);
}

// One 32(q-rows) x 32(j) subtile from LDS tiles (XOR-swizzled layout).
__device__ __forceinline__ void attn_sub2(const __hip_bfloat16* kbase,
                                          const __hip_bfloat16* vbase,
                                          int s, int l31, int hi,
                                          s16x8 qb0, s16x8 qb1,
                                          f32x16& O, float& lsum) {
  int krx = l31 & 3, vrx = l31 & 7;
  const __hip_bfloat16* krow = kbase + (s * 32 + l31) * DIMH;
  s16x8 kf0 = *(const s16x8*)(krow + (((hi) ^ krx) << 3));
  s16x8 kf1 = *(const s16x8*)(krow + (((2 + hi) ^ krx) << 3));
  f32x16 z = {};
  f32x16 sv = __builtin_amdgcn_mfma_f32_32x32x16_bf16(kf0, qb0, z, 0, 0, 0);
  sv        = __builtin_amdgcn_mfma_f32_32x32x16_bf16(kf1, qb1, sv, 0, 0, 0);
  float p[16];
#pragma unroll
  for (int r = 0; r < 16; ++r) p[r] = __builtin_amdgcn_exp2f(sv[r]);
  float t0 = 0.f, t1 = 0.f;
#pragma unroll
  for (int r = 0; r < 16; r += 2) { t0 += p[r]; t1 += p[r + 1]; }
  lsum += t0 + t1;
  unsigned wA[4], wB[4];
#pragma unroll
  for (int m = 0; m < 4; ++m) {
    wA[m] = cvtpk_bf16(p[4 * m], p[4 * m + 1]);
    wB[m] = cvtpk_bf16(p[4 * m + 2], p[4 * m + 3]);
  }
  const __hip_bfloat16* vrow = vbase + l31 * 64;
#define PV_CHUNK(c2, vfrag)                                                    \
  {                                                                            \
    unsigned a0 = wA[2 * (c2)], a1 = wA[2 * (c2) + 1];                         \
    unsigned b0 = wB[2 * (c2)], b1 = wB[2 * (c2) + 1];                         \
    asm("v_permlane32_swap_b32 %0, %1" : "+v"(a0), "+v"(a1));                  \
    asm("v_permlane32_swap_b32 %0, %1" : "+v"(b0), "+v"(b1));                  \
    union { unsigned u[4]; s16x8 v; } pa;                                      \
    pa.u[0] = a0; pa.u[1] = b0; pa.u[2] = a1; pa.u[3] = b1;                    \
    O = __builtin_amdgcn_mfma_f32_32x32x16_bf16(pa.v, vfrag, O, 0, 0, 0);      \
  }
#pragma unroll
  for (int c2 = 0; c2 < 2; ++c2) {
    int cc = s * 2 + c2;
    s16x8 vf = *(const s16x8*)(vrow + (((cc * 2 + hi) ^ vrx) << 3));
    PV_CHUNK(c2, vf);
  }
#undef PV_CHUNK
}

__global__ __launch_bounds__(1024, 4) void k_attn(const __hip_bfloat16* __restrict__ Qt,
                                                  const __hip_bfloat16* __restrict__ Kt,
                                                  const __hip_bfloat16* __restrict__ Vb,
                                                  float* __restrict__ Ot2) {
  int bh = blockIdx.x & 7, qt = blockIdx.x >> 3;   // 8 bh x 32 qt
  int tid = threadIdx.x, lane = tid & 63, wave = tid >> 6;
  int qsub = wave & 3, jq = wave >> 2;
  int l31 = lane & 31, hi = lane >> 5;
  int i0 = qt * 128 + qsub * 32;
  int jbase = jq * 1024;

  __shared__ alignas(16) __hip_bfloat16 Ks[4][2][2048];
  __shared__ alignas(16) __hip_bfloat16 Vs[4][2][2048];
  __shared__ float Olds[4][3][16][68];
  __shared__ float Llds[16][64];

  const __hip_bfloat16* kg = Kt + (size_t)bh * NSP * DIMH;
  const __hip_bfloat16* vg = Vb + (size_t)bh * DIMH * NSP;
  const __hip_bfloat16* qp = Qt + ((size_t)bh * NSP + i0 + l31) * DIMH + hi * 8;
  s16x8 qb0 = *(const s16x8*)qp;
  s16x8 qb1 = *(const s16x8*)(qp + 16);

  int ku = qsub * 64 + lane;
  int krow = ku >> 2;
  int kchunk = (ku & 3) ^ (krow & 3);
  const __hip_bfloat16* ksrc0 = kg + (size_t)krow * DIMH + (kchunk << 3);
  int vd = ku >> 3;
  int vchunk = (ku & 7) ^ (vd & 7);
  const __hip_bfloat16* vsrc0 = vg + (size_t)vd * NSP + (vchunk << 3);
  int lbase = qsub * 512;

  f32x16 O = {};
  float ls0 = 0.f, ls1 = 0.f;

  glds16(ksrc0 + (size_t)jbase * DIMH, &Ks[jq][0][lbase]);
  glds16(vsrc0 + jbase,                &Vs[jq][0][lbase]);
  asm volatile("s_waitcnt vmcnt(0)" ::: "memory");
  __syncthreads();

#pragma unroll 1
  for (int t = 0; t < 16; ++t) {
    int buf = t & 1;
    if (t < 15) {
      int j1 = jbase + (t + 1) * 64;
      glds16(ksrc0 + (size_t)j1 * DIMH, &Ks[jq][buf ^ 1][lbase]);
      glds16(vsrc0 + j1,                &Vs[jq][buf ^ 1][lbase]);
    }
    const __hip_bfloat16* kbase = &Ks[jq][buf][0];
    const __hip_bfloat16* vbase = &Vs[jq][buf][0];
    attn_sub2(kbase, vbase, 0, l31, hi, qb0, qb1, O, ls0);
    attn_sub2(kbase, vbase, 1, l31, hi, qb0, qb1, O, ls1);
    if (t < 15) {
      asm volatile("s_waitcnt vmcnt(0)" ::: "memory");
      __syncthreads();
    }
  }

  float lsum = ls0 + ls1;
  float lw = lsum + __shfl_xor(lsum, 32);
  if (jq) {
#pragma unroll
    for (int r = 0; r < 16; ++r) Olds[qsub][jq - 1][r][lane] = O[r];
  }
  Llds[wave][lane] = lw;
  __syncthreads();
  if (jq == 0) {
    float ltot = lw + Llds[wave + 4][lane] + Llds[wave + 8][lane] + Llds[wave + 12][lane];
    if (hi == 0) Llds[wave][l31] = ltot;
#pragma unroll
    for (int r = 0; r < 16; ++r) {
      int i = (r & 3) + 8 * (r >> 2) + 4 * hi;
      float li = Llds[wave][i];
      float sum = O[r] + Olds[qsub][0][r][lane] + Olds[qsub][1][r][lane] + Olds[qsub][2][r][lane];
      Olds[qsub][0][r][lane] = sum / li;
    }
  }
  __syncthreads();
  {
    int n = tid & 31, dgrp = (tid >> 5) & 7, q2 = tid >> 8;
    int r = (n & 3) | ((n >> 3) << 2);
    int h2 = (n >> 2) & 1;
    float* obase = Ot2 + (size_t)bh * DIMH * NSP + qt * 128 + q2 * 32 + n;
#pragma unroll
    for (int k2 = 0; k2 < 4; ++k2) {
      int d = dgrp * 4 + k2;
      obase[(size_t)d * NSP] = Olds[q2][0][r][h2 * 32 + d];
    }
  }
}

// ---------------- output projection: fp32 channel GEMM, XCD-localized cols ----------------
__global__ __launch_bounds__(128, 8) void k_proj(const float* __restrict__ Ot2,
                                                 const float* __restrict__ w,
                                                 const float* __restrict__ bias,
                                                 float* __restrict__ out) {
  int xcd = blockIdx.x & 7;
  int idx = blockIdx.x >> 3;          // 0..127
  int oc  = idx >> 3;                 // 0..15
  int ct  = xcd * 8 + (idx & 7);      // 0..63, XCD-localized
  int g = ct * 128 + threadIdx.x;
  int b = g >> 12, n = g & 4095;
  const float* op = Ot2 + (size_t)b * HID * NSP + n;
  float acc[8];
#pragma unroll
  for (int i = 0; i < 8; ++i) acc[i] = bias[oc * 8 + i];
#pragma unroll 1
  for (int c0 = 0; c0 < HID; c0 += 32) {
    float cache[32];
#pragma unroll
    for (int cc = 0; cc < 32; ++cc) cache[cc] = op[(size_t)(c0 + cc) * NSP];
#pragma unroll
    for (int cc = 0; cc < 32; ++cc)
#pragma unroll
      for (int i = 0; i < 8; ++i)
        acc[i] += w[(oc * 8 + i) * HID + c0 + cc] * cache[cc];
  }
  float* outb = out + (size_t)b * DIM * NSP + n;
#pragma unroll
  for (int i = 0; i < 8; ++i) outb[(size_t)(oc * 8 + i) * NSP] = acc[i];
}

extern "C" void kernel_launch(void* const* d_in, const int* in_sizes, int n_in,
                              void* d_out, int out_size, void* d_ws, size_t ws_size,
                              hipStream_t stream) {
  const float* x     = (const float*)d_in[0];
  const float* y     = (const float*)d_in[1];
  const float* w_qkv = (const float*)d_in[2];
  const float* w_out = (const float*)d_in[3];
  const float* b_out = (const float*)d_in[4];
  float* out = (float*)d_out;

  char* ws = (char*)d_ws;
  __hip_bfloat16* xt  = (__hip_bfloat16*)(ws);              // 2 MB
  __hip_bfloat16* yt  = (__hip_bfloat16*)(ws + (2  << 20)); // 2 MB
  __hip_bfloat16* Qr  = (__hip_bfloat16*)(ws + (4  << 20)); // 2 MB
  __hip_bfloat16* Kr  = (__hip_bfloat16*)(ws + (6  << 20)); // 2 MB
  __hip_bfloat16* Vb  = (__hip_bfloat16*)(ws + (8  << 20)); // 2 MB
  float* Ot2          = (float*)(ws + (10 << 20));          // 4 MB (channel-major)
  float* ssp          = (float*)(ws + (14 << 20));          // 128 KB partial sums

  k_cvt   <<<256,  256,  0, stream>>>(x, y, xt, yt);
  k_qkvm  <<<384,  256,  0, stream>>>(xt, yt, w_qkv, ssp, Qr, Kr, Vb);
  k_scale <<<256,  256,  0, stream>>>(ssp, Qr, Kr);
  k_attn  <<<256,  1024, 0, stream>>>(Qr, Kr, Vb, Ot2);
  k_proj  <<<1024, 128,  0, stream>>>(Ot2, w_out, b_out, out);
}

// Round 11
// 77.272 us; speedup vs baseline: 3.1258x; 1.0237x over previous
//
#include <hip/hip_runtime.h>
#include <hip/hip_bf16.h>

#define HEADS 4
#define DIMH  32
#define HID   128
#define DIM   128
#define NSP   4096
// 10 * log2(e); folded into the per-channel factor f = scq*sck*QSCALE_LOG2E.
#define QSCALE_LOG2E 14.426950408889634f

typedef __attribute__((ext_vector_type(4)))  float f32x4;
typedef __attribute__((ext_vector_type(16))) float f32x16;
typedef __attribute__((ext_vector_type(8)))  short s16x8;

__device__ __forceinline__ unsigned cvtpk_bf16(float a, float b) {
  unsigned d;
  asm("v_cvt_pk_bf16_f32 %0, %1, %2" : "=v"(d) : "v"(a), "v"(b));
  return d;
}

// ---------------- convert+transpose x,y fp32 [b][c][n] -> bf16 [b*n][c] ----------------
__global__ __launch_bounds__(256) void k_cvt(const float* __restrict__ x,
                                             const float* __restrict__ y,
                                             __hip_bfloat16* __restrict__ xt,
                                             __hip_bfloat16* __restrict__ yt) {
  int bid = blockIdx.x;          // 2 tensor * 2 b * 64 ntiles
  int t = bid >> 7, rem = bid & 127;
  int b = rem >> 6, nt = rem & 63;
  int n0 = nt * 64;
  const float* src = (t ? y : x) + (size_t)b * DIM * NSP;
  __hip_bfloat16* dst = (t ? yt : xt) + (size_t)b * NSP * DIM;

  __shared__ alignas(16) __hip_bfloat16 tile[64 * 136];
  int c = threadIdx.x >> 1, nh = (threadIdx.x & 1) * 32;
  const float* sp = src + (size_t)c * NSP + n0 + nh;
#pragma unroll
  for (int i = 0; i < 32; ++i)
    tile[(nh + i) * 136 + c] = __float2bfloat16(sp[i]);
  __syncthreads();
  int rrow = threadIdx.x >> 2, cb = (threadIdx.x & 3) * 32;
  __hip_bfloat16* op = dst + (size_t)(n0 + rrow) * DIM + cb;
  const __hip_bfloat16* ip = tile + rrow * 136 + cb;
#pragma unroll
  for (int k = 0; k < 4; ++k)
    *(s16x8*)(op + k * 8) = *(const s16x8*)(ip + k * 8);
}

// ---------------- QKV GEMM on MFMA: D[orow][n] = sum_c W[orow][c] * src[n][c] ----------------
// orows 0..127 = Q (fp32 out, from xt), 128..255 = K (bf16, from yt), 256..383 = V (bf16, from yt).
// Qf fp32 [bh][n][32] (unnormalized), Kr bf16 [bh][n][32] (unnormalized), Vb bf16 [bh][d][n].
// Sum-of-squares: deterministic per-wave partials into ssp[512][64] (no atomics).
__global__ __launch_bounds__(256, 4) void k_qkvm(const __hip_bfloat16* __restrict__ xt,
                                                 const __hip_bfloat16* __restrict__ yt,
                                                 const float* __restrict__ w,
                                                 float* __restrict__ ssp,
                                                 float* __restrict__ Qf,
                                                 __hip_bfloat16* __restrict__ Kr,
                                                 __hip_bfloat16* __restrict__ Vb) {
  int xcd = blockIdx.x & 7;
  int r = blockIdx.x >> 3;        // 0..47
  int ot = r >> 2;                // 0..11
  int nts = r & 3;
  int tile = xcd * 4 + nts;       // n-tile 0..31
  int n0 = tile * 256;            // global n base (0..8191)
  int lane = threadIdx.x & 63, wave = threadIdx.x >> 6;
  int l31 = lane & 31, hi = lane >> 5;
  int orow = ot * 32 + l31;

  // A-fragments: W row `orow`, bf16; step k covers c = k*16 + hi*8 + 0..7
  s16x8 wf[8];
  const float* wr = w + orow * DIM + hi * 8;
#pragma unroll
  for (int k = 0; k < 8; ++k) {
    f32x4 a = *(const f32x4*)(wr + k * 16);
    f32x4 b2 = *(const f32x4*)(wr + k * 16 + 4);
    union { unsigned u[4]; s16x8 v; } p;
    p.u[0] = cvtpk_bf16(a[0], a[1]);
    p.u[1] = cvtpk_bf16(a[2], a[3]);
    p.u[2] = cvtpk_bf16(b2[0], b2[1]);
    p.u[3] = cvtpk_bf16(b2[2], b2[3]);
    wf[k] = p.v;
  }

  const __hip_bfloat16* src = (ot < 4 ? xt : yt);
  int nw = n0 + wave * 64;
  f32x16 acc0 = {}, acc1 = {};
#pragma unroll
  for (int k = 0; k < 8; ++k) {
    s16x8 b0 = *(const s16x8*)(src + (size_t)(nw + l31) * DIM + k * 16 + hi * 8);
    s16x8 b1 = *(const s16x8*)(src + (size_t)(nw + 32 + l31) * DIM + k * 16 + hi * 8);
    acc0 = __builtin_amdgcn_mfma_f32_32x32x16_bf16(wf[k], b0, acc0, 0, 0, 0);
    acc1 = __builtin_amdgcn_mfma_f32_32x32x16_bf16(wf[k], b1, acc1, 0, 0, 0);
  }

  int b = nw >> 12;               // batch (256-n tiles never straddle)
  if (ot < 8) {
    int h = ot & 3;
    if (ot < 4) {
      // Q fp32: [bh][n][32]; regs 4m..4m+3 -> d = 8m+4hi+0..3 (contiguous f32x4)
#pragma unroll
      for (int nt = 0; nt < 2; ++nt) {
        int np = (nw + nt * 32 + l31) & 4095;
        float* base = Qf + ((size_t)((b * HEADS + h) * NSP + np)) * DIMH;
        const f32x16& A = nt ? acc1 : acc0;
#pragma unroll
        for (int m = 0; m < 4; ++m) {
          f32x4 v = { A[4 * m], A[4 * m + 1], A[4 * m + 2], A[4 * m + 3] };
          *(f32x4*)(base + 8 * m + 4 * hi) = v;
        }
      }
    } else {
      // K bf16: [bh][n][32]
#pragma unroll
      for (int nt = 0; nt < 2; ++nt) {
        int np = (nw + nt * 32 + l31) & 4095;
        __hip_bfloat16* base = Kr + ((size_t)((b * HEADS + h) * NSP + np)) * DIMH;
        const f32x16& A = nt ? acc1 : acc0;
#pragma unroll
        for (int m = 0; m < 4; ++m) {
          uint2 p2;
          p2.x = cvtpk_bf16(A[4 * m], A[4 * m + 1]);
          p2.y = cvtpk_bf16(A[4 * m + 2], A[4 * m + 3]);
          *(uint2*)(base + 8 * m + 4 * hi) = p2;
        }
      }
    }
    // ---- sum-of-squares partials: one slot per (row, tile-in-batch, wave) ----
    float p[16];
#pragma unroll
    for (int r2 = 0; r2 < 16; ++r2) p[r2] = acc0[r2] * acc0[r2] + acc1[r2] * acc1[r2];
#pragma unroll
    for (int r2 = 0; r2 < 16; ++r2) {
#pragma unroll
      for (int m2 = 1; m2 < 32; m2 <<= 1) p[r2] += __shfl_xor(p[r2], m2);
    }
    if (l31 == 0) {
      int t = (ot < 4 ? 0 : 1);
      int widx = (tile & 15) * 4 + wave;              // 0..63
      int rbase = (t * 2 + b) * 128 + h * 32;
#pragma unroll
      for (int r2 = 0; r2 < 16; ++r2) {
        int row = (r2 & 3) + 8 * (r2 >> 2) + 4 * hi;
        ssp[(size_t)(rbase + row) * 64 + widx] = p[r2];
      }
    }
  } else {
    // V: [bh][d][n]
    int h = ot - 8;
#pragma unroll
    for (int nt = 0; nt < 2; ++nt) {
      int np = (nw + nt * 32 + l31) & 4095;
      const f32x16& A = nt ? acc1 : acc0;
#pragma unroll
      for (int r2 = 0; r2 < 16; ++r2) {
        int d = (r2 & 3) + 8 * (r2 >> 2) + 4 * hi;
        Vb[((size_t)((b * HEADS + h) * DIMH + d)) * NSP + np] = __float2bfloat16(A[r2]);
      }
    }
  }
}

// ---------------- reduce ssp -> per-channel combined factor f[bh][32] ----------------
// f = rsqrt(ssq)*rsqrt(ssk)*QSCALE_LOG2E   (8 blocks, one per bh)
__global__ __launch_bounds__(512) void k_fac(const float* __restrict__ ssp,
                                             float* __restrict__ fsc) {
  int bh = blockIdx.x;            // 0..7
  int b = bh >> 2, h = bh & 3;
  int tid = threadIdx.x;          // 512 = 2qk * 32d * 8jj
  int qk = tid >> 8, d = (tid >> 3) & 31, jj = tid & 7;
  const float* pp = ssp + (size_t)((qk * 2 + b) * 128 + h * 32 + d) * 64 + jj * 8;
  float s = 0.f;
#pragma unroll
  for (int k = 0; k < 8; ++k) s += pp[k];
  s += __shfl_down(s, 1); s += __shfl_down(s, 2); s += __shfl_down(s, 4);
  __shared__ float red[2][32];
  if (jj == 0) red[qk][d] = s;
  __syncthreads();
  if (tid < 32) {
    float vq = 1.f / fmaxf(sqrtf(red[0][tid]), 0.1f);
    float vk = 1.f / fmaxf(sqrtf(red[1][tid]), 0.1f);
    fsc[bh * 32 + tid] = vq * vk * QSCALE_LOG2E;
  }
}

// ---------------- flash attention: LDS-staged K/V, 32x32x16 MFMA, in-reg softmax ----------------
__device__ __forceinline__ void glds16(const __hip_bfloat16* g, __hip_bfloat16* l) {
  __builtin_amdgcn_global_load_lds(
      (const __attribute__((address_space(1))) unsigned int*)(const void*)g,
      (__attribute__((address_space(3))) unsigned int*)(void*)l, 16, 0, 0);
}

// One 32(q-rows) x 32(j) subtile from LDS tiles (XOR-swizzled layout).
__device__ __forceinline__ void attn_sub2(const __hip_bfloat16* kbase,
                                          const __hip_bfloat16* vbase,
                                          int s, int l31, int hi,
                                          s16x8 qb0, s16x8 qb1,
                                          f32x16& O, float& lsum) {
  int krx = l31 & 3, vrx = l31 & 7;
  const __hip_bfloat16* krow = kbase + (s * 32 + l31) * DIMH;
  s16x8 kf0 = *(const s16x8*)(krow + (((hi) ^ krx) << 3));
  s16x8 kf1 = *(const s16x8*)(krow + (((2 + hi) ^ krx) << 3));
  f32x16 z = {};
  f32x16 sv = __builtin_amdgcn_mfma_f32_32x32x16_bf16(kf0, qb0, z, 0, 0, 0);
  sv        = __builtin_amdgcn_mfma_f32_32x32x16_bf16(kf1, qb1, sv, 0, 0, 0);
  float p[16];
#pragma unroll
  for (int r = 0; r < 16; ++r) p[r] = __builtin_amdgcn_exp2f(sv[r]);
  float t0 = 0.f, t1 = 0.f;
#pragma unroll
  for (int r = 0; r < 16; r += 2) { t0 += p[r]; t1 += p[r + 1]; }
  lsum += t0 + t1;
  unsigned wA[4], wB[4];
#pragma unroll
  for (int m = 0; m < 4; ++m) {
    wA[m] = cvtpk_bf16(p[4 * m], p[4 * m + 1]);
    wB[m] = cvtpk_bf16(p[4 * m + 2], p[4 * m + 3]);
  }
  const __hip_bfloat16* vrow = vbase + l31 * 64;
#define PV_CHUNK(c2, vfrag)                                                    \
  {                                                                            \
    unsigned a0 = wA[2 * (c2)], a1 = wA[2 * (c2) + 1];                         \
    unsigned b0 = wB[2 * (c2)], b1 = wB[2 * (c2) + 1];                         \
    asm("v_permlane32_swap_b32 %0, %1" : "+v"(a0), "+v"(a1));                  \
    asm("v_permlane32_swap_b32 %0, %1" : "+v"(b0), "+v"(b1));                  \
    union { unsigned u[4]; s16x8 v; } pa;                                      \
    pa.u[0] = a0; pa.u[1] = b0; pa.u[2] = a1; pa.u[3] = b1;                    \
    O = __builtin_amdgcn_mfma_f32_32x32x16_bf16(pa.v, vfrag, O, 0, 0, 0);      \
  }
#pragma unroll
  for (int c2 = 0; c2 < 2; ++c2) {
    int cc = s * 2 + c2;
    s16x8 vf = *(const s16x8*)(vrow + (((cc * 2 + hi) ^ vrx) << 3));
    PV_CHUNK(c2, vf);
  }
#undef PV_CHUNK
}

__global__ __launch_bounds__(1024, 4) void k_attn(const float* __restrict__ Qf,
                                                  const __hip_bfloat16* __restrict__ Kt,
                                                  const __hip_bfloat16* __restrict__ Vb,
                                                  const float* __restrict__ fsc,
                                                  float* __restrict__ Ot2) {
  int bh = blockIdx.x & 7, qt = blockIdx.x >> 3;   // 8 bh x 32 qt
  int tid = threadIdx.x, lane = tid & 63, wave = tid >> 6;
  int qsub = wave & 3, jq = wave >> 2;
  int l31 = lane & 31, hi = lane >> 5;
  int i0 = qt * 128 + qsub * 32;
  int jbase = jq * 1024;

  __shared__ alignas(16) __hip_bfloat16 Ks[4][2][2048];
  __shared__ alignas(16) __hip_bfloat16 Vs[4][2][2048];
  __shared__ float Olds[4][3][16][68];
  __shared__ float Llds[16][64];

  const __hip_bfloat16* kg = Kt + (size_t)bh * NSP * DIMH;
  const __hip_bfloat16* vg = Vb + (size_t)bh * DIMH * NSP;

  // Q fragment: fp32 load, scale by per-channel factor f, pack to bf16 (single rounding)
  const float* qpf = Qf + ((size_t)bh * NSP + i0 + l31) * DIMH;
  const float* fb = fsc + bh * 32;
  s16x8 qb0, qb1;
  {
    f32x4 a0 = *(const f32x4*)(qpf + hi * 8);
    f32x4 a1 = *(const f32x4*)(qpf + hi * 8 + 4);
    f32x4 a2 = *(const f32x4*)(qpf + 16 + hi * 8);
    f32x4 a3 = *(const f32x4*)(qpf + 16 + hi * 8 + 4);
    f32x4 f0 = *(const f32x4*)(fb + hi * 8);
    f32x4 f1 = *(const f32x4*)(fb + hi * 8 + 4);
    f32x4 f2 = *(const f32x4*)(fb + 16 + hi * 8);
    f32x4 f3 = *(const f32x4*)(fb + 16 + hi * 8 + 4);
    union { unsigned u[4]; s16x8 v; } p0, p1;
    p0.u[0] = cvtpk_bf16(a0[0] * f0[0], a0[1] * f0[1]);
    p0.u[1] = cvtpk_bf16(a0[2] * f0[2], a0[3] * f0[3]);
    p0.u[2] = cvtpk_bf16(a1[0] * f1[0], a1[1] * f1[1]);
    p0.u[3] = cvtpk_bf16(a1[2] * f1[2], a1[3] * f1[3]);
    p1.u[0] = cvtpk_bf16(a2[0] * f2[0], a2[1] * f2[1]);
    p1.u[1] = cvtpk_bf16(a2[2] * f2[2], a2[3] * f2[3]);
    p1.u[2] = cvtpk_bf16(a3[0] * f3[0], a3[1] * f3[1]);
    p1.u[3] = cvtpk_bf16(a3[2] * f3[2], a3[3] * f3[3]);
    qb0 = p0.v; qb1 = p1.v;
  }

  int ku = qsub * 64 + lane;
  int krow = ku >> 2;
  int kchunk = (ku & 3) ^ (krow & 3);
  const __hip_bfloat16* ksrc0 = kg + (size_t)krow * DIMH + (kchunk << 3);
  int vd = ku >> 3;
  int vchunk = (ku & 7) ^ (vd & 7);
  const __hip_bfloat16* vsrc0 = vg + (size_t)vd * NSP + (vchunk << 3);
  int lbase = qsub * 512;

  f32x16 O = {};
  float ls0 = 0.f, ls1 = 0.f;

  glds16(ksrc0 + (size_t)jbase * DIMH, &Ks[jq][0][lbase]);
  glds16(vsrc0 + jbase,                &Vs[jq][0][lbase]);
  asm volatile("s_waitcnt vmcnt(0)" ::: "memory");
  __syncthreads();

#pragma unroll 1
  for (int t = 0; t < 16; ++t) {
    int buf = t & 1;
    if (t < 15) {
      int j1 = jbase + (t + 1) * 64;
      glds16(ksrc0 + (size_t)j1 * DIMH, &Ks[jq][buf ^ 1][lbase]);
      glds16(vsrc0 + j1,                &Vs[jq][buf ^ 1][lbase]);
    }
    const __hip_bfloat16* kbase = &Ks[jq][buf][0];
    const __hip_bfloat16* vbase = &Vs[jq][buf][0];
    attn_sub2(kbase, vbase, 0, l31, hi, qb0, qb1, O, ls0);
    attn_sub2(kbase, vbase, 1, l31, hi, qb0, qb1, O, ls1);
    if (t < 15) {
      asm volatile("s_waitcnt vmcnt(0)" ::: "memory");
      __syncthreads();
    }
  }

  float lsum = ls0 + ls1;
  float lw = lsum + __shfl_xor(lsum, 32);
  if (jq) {
#pragma unroll
    for (int r = 0; r < 16; ++r) Olds[qsub][jq - 1][r][lane] = O[r];
  }
  Llds[wave][lane] = lw;
  __syncthreads();
  if (jq == 0) {
    float ltot = lw + Llds[wave + 4][lane] + Llds[wave + 8][lane] + Llds[wave + 12][lane];
    if (hi == 0) Llds[wave][l31] = ltot;
#pragma unroll
    for (int r = 0; r < 16; ++r) {
      int i = (r & 3) + 8 * (r >> 2) + 4 * hi;
      float li = Llds[wave][i];
      float sum = O[r] + Olds[qsub][0][r][lane] + Olds[qsub][1][r][lane] + Olds[qsub][2][r][lane];
      Olds[qsub][0][r][lane] = sum / li;
    }
  }
  __syncthreads();
  {
    int n = tid & 31, dgrp = (tid >> 5) & 7, q2 = tid >> 8;
    int r = (n & 3) | ((n >> 3) << 2);
    int h2 = (n >> 2) & 1;
    float* obase = Ot2 + (size_t)bh * DIMH * NSP + qt * 128 + q2 * 32 + n;
#pragma unroll
    for (int k2 = 0; k2 < 4; ++k2) {
      int d = dgrp * 4 + k2;
      obase[(size_t)d * NSP] = Olds[q2][0][r][h2 * 32 + d];
    }
  }
}

// ---------------- output projection: fp32 channel GEMM, XCD-localized cols ----------------
__global__ __launch_bounds__(128, 8) void k_proj(const float* __restrict__ Ot2,
                                                 const float* __restrict__ w,
                                                 const float* __restrict__ bias,
                                                 float* __restrict__ out) {
  int xcd = blockIdx.x & 7;
  int idx = blockIdx.x >> 3;          // 0..127
  int oc  = idx >> 3;                 // 0..15
  int ct  = xcd * 8 + (idx & 7);      // 0..63, XCD-localized
  int g = ct * 128 + threadIdx.x;
  int b = g >> 12, n = g & 4095;
  const float* op = Ot2 + (size_t)b * HID * NSP + n;
  float acc[8];
#pragma unroll
  for (int i = 0; i < 8; ++i) acc[i] = bias[oc * 8 + i];
#pragma unroll 1
  for (int c0 = 0; c0 < HID; c0 += 32) {
    float cache[32];
#pragma unroll
    for (int cc = 0; cc < 32; ++cc) cache[cc] = op[(size_t)(c0 + cc) * NSP];
#pragma unroll
    for (int cc = 0; cc < 32; ++cc)
#pragma unroll
      for (int i = 0; i < 8; ++i)
        acc[i] += w[(oc * 8 + i) * HID + c0 + cc] * cache[cc];
  }
  float* outb = out + (size_t)b * DIM * NSP + n;
#pragma unroll
  for (int i = 0; i < 8; ++i) outb[(size_t)(oc * 8 + i) * NSP] = acc[i];
}

extern "C" void kernel_launch(void* const* d_in, const int* in_sizes, int n_in,
                              void* d_out, int out_size, void* d_ws, size_t ws_size,
                              hipStream_t stream) {
  const float* x     = (const float*)d_in[0];
  const float* y     = (const float*)d_in[1];
  const float* w_qkv = (const float*)d_in[2];
  const float* w_out = (const float*)d_in[3];
  const float* b_out = (const float*)d_in[4];
  float* out = (float*)d_out;

  char* ws = (char*)d_ws;
  __hip_bfloat16* xt  = (__hip_bfloat16*)(ws);              // 2 MB
  __hip_bfloat16* yt  = (__hip_bfloat16*)(ws + (2  << 20)); // 2 MB
  float* Qf           = (float*)(ws + (4  << 20));          // 4 MB (fp32, unnormalized)
  __hip_bfloat16* Kr  = (__hip_bfloat16*)(ws + (8  << 20)); // 2 MB (bf16, unnormalized)
  __hip_bfloat16* Vb  = (__hip_bfloat16*)(ws + (10 << 20)); // 2 MB
  float* Ot2          = (float*)(ws + (12 << 20));          // 4 MB (channel-major)
  float* ssp          = (float*)(ws + (16 << 20));          // 128 KB partial sums
  float* fsc          = (float*)(ws + (16 << 20) + (128 << 10)); // 1 KB factors

  k_cvt   <<<256,  256,  0, stream>>>(x, y, xt, yt);
  k_qkvm  <<<384,  256,  0, stream>>>(xt, yt, w_qkv, ssp, Qf, Kr, Vb);
  k_fac   <<<8,    512,  0, stream>>>(ssp, fsc);
  k_attn  <<<256,  1024, 0, stream>>>(Qf, Kr, Vb, fsc, Ot2);
  k_proj  <<<1024, 128,  0, stream>>>(Ot2, w_out, b_out, out);
}